// Round 23
// baseline (365.047 us; speedup 1.0000x reference)
//
#include <hip/hip_runtime.h>

#define NODE_DIM 256
#define HIDDEN 64
#define NUM_REL 10

#define FMA4(A, S, W) do { \
    (A).x = fmaf((S), (W).x, (A).x); \
    (A).y = fmaf((S), (W).y, (A).y); \
    (A).z = fmaf((S), (W).z, (A).z); \
    (A).w = fmaf((S), (W).w, (A).w); } while (0)

#define ELEM(V, I) ((I) == 0 ? (V).x : (I) == 1 ? (V).y : (I) == 2 ? (V).z : (V).w)

// Edge kernel: R22 with ONE change — the two k4 loops are FULLY UNROLLED
// (R13-R22 used unroll 1, which walls off each iteration's ds_read + s_load
// batch behind a full lgkm drain with no cross-iteration prefetch; full
// unroll gives the scheduler a single window to hoist loads under the FMA
// stream with counted lgkmcnt waits). Unrolling does not change FP order ->
// bit-identical. Dataflow: 32 KB per-thread LDS scratch, Hc row staged in
// two 8-quad chunks, each 128B line fetched once; np chain order: k
// ascending over W3 rows 64..127, +b3 after, relu, j-ascending logits, +b4.
__global__ __launch_bounds__(256, 2) void edge_kernel(
    const int* __restrict__ ei,
    const float* __restrict__ H, const float* __restrict__ A,
    const float* __restrict__ W3, const float* __restrict__ b3,
    const float* __restrict__ W4, const float* __restrict__ b4,
    float* __restrict__ out_type, float* __restrict__ out_probs, int E)
{
    __shared__ float4 HcS[256 * 8];   // 32 KB: per-thread 8-quad scratch

    const int tid = threadIdx.x;
    const int e = blockIdx.x * 256 + tid;
    const bool valid = (e < E);
    const int sw = tid & 7;
    float4* myscr = &HcS[tid * 8];

    const int c = valid ? ei[E + e] : 0;
    const int r = valid ? ei[e] : 0;
    const float4* src = (const float4*)(H + (size_t)c * 64);
    const float4* Ar  = (const float4*)(A + (size_t)r * 64);

    // stage chunk 0: Hc quads 0..7
    #pragma unroll
    for (int q = 0; q < 8; ++q) myscr[q ^ sw] = src[q];

    // seed 64 scalar accumulators from the A chain prefix (one-shot gather)
    float acc[64];
    #pragma unroll
    for (int j4 = 0; j4 < 16; ++j4) {
        float4 v = Ar[j4];
        acc[4 * j4 + 0] = v.x; acc[4 * j4 + 1] = v.y;
        acc[4 * j4 + 2] = v.z; acc[4 * j4 + 3] = v.w;
    }

    const float* W3b = W3 + 64 * 64;

    // chunk 0: k4 = 0..7 (W3 rows 64..95, ascending) — FULLY UNROLLED
    #pragma unroll
    for (int k4 = 0; k4 < 8; ++k4) {
        const float4 hv = myscr[k4 ^ sw];
        #pragma unroll
        for (int i = 0; i < 4; ++i) {
            const float s = ELEM(hv, i);
            const float* w = W3b + (size_t)(k4 * 4 + i) * 64;
            #pragma unroll
            for (int j4 = 0; j4 < 16; ++j4) {
                float4 wv = *(const float4*)(w + 4 * j4);
                acc[4 * j4 + 0] = fmaf(s, wv.x, acc[4 * j4 + 0]);
                acc[4 * j4 + 1] = fmaf(s, wv.y, acc[4 * j4 + 1]);
                acc[4 * j4 + 2] = fmaf(s, wv.z, acc[4 * j4 + 2]);
                acc[4 * j4 + 3] = fmaf(s, wv.w, acc[4 * j4 + 3]);
            }
        }
    }

    // restage chunk 1: Hc quads 8..15 (same L2 lines, fetched once)
    #pragma unroll
    for (int q = 0; q < 8; ++q) myscr[q ^ sw] = src[8 + q];

    // chunk 1: k4 = 8..15 (W3 rows 96..127, ascending) — FULLY UNROLLED
    #pragma unroll
    for (int k4 = 8; k4 < 16; ++k4) {
        const float4 hv = myscr[(k4 - 8) ^ sw];
        #pragma unroll
        for (int i = 0; i < 4; ++i) {
            const float s = ELEM(hv, i);
            const float* w = W3b + (size_t)(k4 * 4 + i) * 64;
            #pragma unroll
            for (int j4 = 0; j4 < 16; ++j4) {
                float4 wv = *(const float4*)(w + 4 * j4);
                acc[4 * j4 + 0] = fmaf(s, wv.x, acc[4 * j4 + 0]);
                acc[4 * j4 + 1] = fmaf(s, wv.y, acc[4 * j4 + 1]);
                acc[4 * j4 + 2] = fmaf(s, wv.z, acc[4 * j4 + 2]);
                acc[4 * j4 + 3] = fmaf(s, wv.w, acc[4 * j4 + 3]);
            }
        }
    }

    // + b3, relu (j ascending)
    #pragma unroll
    for (int j = 0; j < 64; ++j)
        acc[j] = fmaxf(acc[j] + b3[j], 0.0f);

    // logits = (hid @ W4) + b4, j ascending
    float lg[NUM_REL];
    #pragma unroll
    for (int j = 0; j < NUM_REL; ++j) lg[j] = 0.0f;
    #pragma unroll
    for (int k = 0; k < 64; ++k) {
        const float s = acc[k];
        const float* wp = W4 + (size_t)k * NUM_REL;
        #pragma unroll
        for (int j = 0; j < NUM_REL; ++j) lg[j] = fmaf(s, wp[j], lg[j]);
    }

    if (!valid) return;

    #pragma unroll
    for (int j = 0; j < NUM_REL; ++j) lg[j] += b4[j];

    // argmax, first occurrence
    int best = 0;
    float bm = lg[0];
    #pragma unroll
    for (int j = 1; j < NUM_REL; ++j)
        if (lg[j] > bm) { bm = lg[j]; best = j; }

    // softmax fp32
    float p[NUM_REL];
    float sum = 0.0f;
    #pragma unroll
    for (int j = 0; j < NUM_REL; ++j) {
        p[j] = expf(lg[j] - bm);
        sum += p[j];
    }
    float inv = 1.0f / sum;

    out_type[e] = (float)best;
    float* op = out_probs + (size_t)e * NUM_REL;
    #pragma unroll
    for (int j = 0; j < NUM_REL; ++j) op[j] = p[j] * inv;
}

// Node pipeline: R17 verbatim (~94 us). Block = 4 waves x 64 lanes; lane =
// node, wave = j-slice via readfirstlane -> SGPR -> s_load weights. h1/h
// handed between layers via LDS [64][65]. Per-element np/BLAS chain: acc=0,
// k ascending fmaf over FULL K, bias AFTER, relu -> bit-identical.
__global__ __launch_bounds__(256, 4) void node_kernel(
    const float* __restrict__ x,
    const float* __restrict__ W1, const float* __restrict__ b1,
    const float* __restrict__ W2, const float* __restrict__ b2,
    const float* __restrict__ W3,
    float* __restrict__ Hout, float* __restrict__ Aout, int N)
{
    __shared__ float h1s[64][65];
    __shared__ float hs[64][65];

    const int tid  = threadIdx.x;
    const int lane = tid & 63;
    const int jb   = __builtin_amdgcn_readfirstlane((tid >> 6) << 4);
    const int n    = blockIdx.x * 64 + lane;
    const bool valid = (n < N);
    const int nc   = valid ? n : (N - 1);

    // ---- L1 slice: h1[jb..jb+16) = relu((x@W1) + b1) ----
    float4 a0 = make_float4(0.f, 0.f, 0.f, 0.f);
    float4 a1 = a0, a2 = a0, a3 = a0;

    const float4* xr = (const float4*)(x + (size_t)nc * NODE_DIM);
    #pragma unroll 1
    for (int k4 = 0; k4 < NODE_DIM / 4; ++k4) {
        float4 xv = xr[k4];
        #pragma unroll
        for (int i = 0; i < 4; ++i) {
            const float s = ELEM(xv, i);
            const float4* w = (const float4*)(W1 + (size_t)(k4 * 4 + i) * 64 + jb);
            float4 w0 = w[0], w1 = w[1], w2 = w[2], w3 = w[3];
            FMA4(a0, s, w0); FMA4(a1, s, w1);
            FMA4(a2, s, w2); FMA4(a3, s, w3);
        }
    }
    {
        const float4* bv = (const float4*)(b1 + jb);
        float4 b0 = bv[0], b1v = bv[1], b2v = bv[2], b3v = bv[3];
        float* d = &h1s[lane][jb];
        d[0]  = fmaxf(a0.x + b0.x, 0.f);  d[1]  = fmaxf(a0.y + b0.y, 0.f);
        d[2]  = fmaxf(a0.z + b0.z, 0.f);  d[3]  = fmaxf(a0.w + b0.w, 0.f);
        d[4]  = fmaxf(a1.x + b1v.x, 0.f); d[5]  = fmaxf(a1.y + b1v.y, 0.f);
        d[6]  = fmaxf(a1.z + b1v.z, 0.f); d[7]  = fmaxf(a1.w + b1v.w, 0.f);
        d[8]  = fmaxf(a2.x + b2v.x, 0.f); d[9]  = fmaxf(a2.y + b2v.y, 0.f);
        d[10] = fmaxf(a2.z + b2v.z, 0.f); d[11] = fmaxf(a2.w + b2v.w, 0.f);
        d[12] = fmaxf(a3.x + b3v.x, 0.f); d[13] = fmaxf(a3.y + b3v.y, 0.f);
        d[14] = fmaxf(a3.z + b3v.z, 0.f); d[15] = fmaxf(a3.w + b3v.w, 0.f);
    }
    __syncthreads();

    // ---- L2 slice: h[jb..jb+16) = (h1@W2) + b2 ----
    a0 = make_float4(0.f, 0.f, 0.f, 0.f); a1 = a0; a2 = a0; a3 = a0;
    #pragma unroll 1
    for (int k = 0; k < 64; ++k) {
        const float s = h1s[lane][k];
        const float4* w = (const float4*)(W2 + (size_t)k * 64 + jb);
        float4 w0 = w[0], w1 = w[1], w2 = w[2], w3 = w[3];
        FMA4(a0, s, w0); FMA4(a1, s, w1);
        FMA4(a2, s, w2); FMA4(a3, s, w3);
    }
    {
        const float4* bv = (const float4*)(b2 + jb);
        float4 b0 = bv[0], b1v = bv[1], b2v = bv[2], b3v = bv[3];
        float4 r0, r1, r2, r3;
        r0.x = a0.x + b0.x;  r0.y = a0.y + b0.y;  r0.z = a0.z + b0.z;  r0.w = a0.w + b0.w;
        r1.x = a1.x + b1v.x; r1.y = a1.y + b1v.y; r1.z = a1.z + b1v.z; r1.w = a1.w + b1v.w;
        r2.x = a2.x + b2v.x; r2.y = a2.y + b2v.y; r2.z = a2.z + b2v.z; r2.w = a2.w + b2v.w;
        r3.x = a3.x + b3v.x; r3.y = a3.y + b3v.y; r3.z = a3.z + b3v.z; r3.w = a3.w + b3v.w;
        float* d = &hs[lane][jb];
        d[0]  = r0.x; d[1]  = r0.y; d[2]  = r0.z; d[3]  = r0.w;
        d[4]  = r1.x; d[5]  = r1.y; d[6]  = r1.z; d[7]  = r1.w;
        d[8]  = r2.x; d[9]  = r2.y; d[10] = r2.z; d[11] = r2.w;
        d[12] = r3.x; d[13] = r3.y; d[14] = r3.z; d[15] = r3.w;
        if (valid) {
            float4* g = (float4*)(Hout + (size_t)n * 64 + jb);
            g[0] = r0; g[1] = r1; g[2] = r2; g[3] = r3;
        }
    }
    __syncthreads();

    // ---- L3 row-half partial slice: A[jb..jb+16) = h @ W3[0:64], no bias ----
    a0 = make_float4(0.f, 0.f, 0.f, 0.f); a1 = a0; a2 = a0; a3 = a0;
    #pragma unroll 1
    for (int k = 0; k < 64; ++k) {
        const float s = hs[lane][k];
        const float4* w = (const float4*)(W3 + (size_t)k * 64 + jb);
        float4 w0 = w[0], w1 = w[1], w2 = w[2], w3 = w[3];
        FMA4(a0, s, w0); FMA4(a1, s, w1);
        FMA4(a2, s, w2); FMA4(a3, s, w3);
    }
    if (valid) {
        float4* g = (float4*)(Aout + (size_t)n * 64 + jb);
        g[0] = a0; g[1] = a1; g[2] = a2; g[3] = a3;
    }
}

extern "C" void kernel_launch(void* const* d_in, const int* in_sizes, int n_in,
                              void* d_out, int out_size, void* d_ws, size_t ws_size,
                              hipStream_t stream)
{
    const float* x  = (const float*)d_in[0];
    const int*   ei = (const int*)d_in[1];
    const float* W1 = (const float*)d_in[2];
    const float* b1 = (const float*)d_in[3];
    const float* W2 = (const float*)d_in[4];
    const float* b2 = (const float*)d_in[5];
    const float* W3 = (const float*)d_in[6];
    const float* b3 = (const float*)d_in[7];
    const float* W4 = (const float*)d_in[8];
    const float* b4 = (const float*)d_in[9];

    int N = in_sizes[0] / NODE_DIM;   // 100000
    int E = in_sizes[1] / 2;          // 1600000

    // ws: H [N*64] f32 | A [N*64] f32   (51.2 MB total)
    float* H = (float*)d_ws;
    float* A = H + (size_t)N * 64;

    int nb = (N + 63) / 64;
    int eb = (E + 255) / 256;

    float* out_type  = (float*)d_out;
    float* out_probs = (float*)d_out + E;

    hipLaunchKernelGGL(node_kernel, dim3(nb), dim3(256), 0, stream,
                       x, W1, b1, W2, b2, W3, H, A, N);
    hipLaunchKernelGGL(edge_kernel, dim3(eb), dim3(256), 0, stream,
                       ei, H, A, W3, b3, W4, b4, out_type, out_probs, E);
}

// Round 24
// 312.230 us; speedup vs baseline: 1.1692x; 1.1692x over previous
//
#include <hip/hip_runtime.h>

#define NODE_DIM 256
#define HIDDEN 64
#define NUM_REL 10

#define FMA4(A, S, W) do { \
    (A).x = fmaf((S), (W).x, (A).x); \
    (A).y = fmaf((S), (W).y, (A).y); \
    (A).z = fmaf((S), (W).z, (A).z); \
    (A).w = fmaf((S), (W).w, (A).w); } while (0)

#define ELEM(V, I) ((I) == 0 ? (V).x : (I) == 1 ? (V).y : (I) == 2 ? (V).z : (V).w)

// Edge kernel: R13 source (the form that achieved ~104 us) with the register
// allocator's occupancy target PINNED to the LDS-capped reality:
// amdgpu_waves_per_eu(4,4) -> target = 4 waves/EU exactly (= 4 blocks/CU, the
// LDS cap), VGPR budget = 512/4 = 128 >= the ~110 the good allocation needs.
// Rationale: R17-R23 showed the allocator picks a 56-VGPR + AGPR-shuttle form
// chasing occupancy it can never reach (LDS-capped) — launch_bounds' min-waves
// arg sets the budget but not the target; this attribute sets both.
// Math/chain order byte-identical to R13: k ascending over W3 rows 64..127,
// +b3 after, relu, j-ascending logits, +b4 -> bit-identical to np.
__global__ __launch_bounds__(256)
__attribute__((amdgpu_waves_per_eu(4, 4)))
void edge_kernel(
    const int* __restrict__ ei,
    const float* __restrict__ H, const float* __restrict__ A,
    const float* __restrict__ W3, const float* __restrict__ b3,
    const float* __restrict__ W4, const float* __restrict__ b4,
    float* __restrict__ out_type, float* __restrict__ out_probs, int E)
{
    __shared__ float4 HcS[256 * 8];   // 32 KB: per-thread 8-quad scratch

    const int tid = threadIdx.x;
    const int e = blockIdx.x * 256 + tid;
    const bool valid = (e < E);
    const int sw = tid & 7;
    float4* myscr = &HcS[tid * 8];

    const int c = valid ? ei[E + e] : 0;
    const int r = valid ? ei[e] : 0;
    const float4* src = (const float4*)(H + (size_t)c * 64);
    const float4* Ar  = (const float4*)(A + (size_t)r * 64);

    // stage chunk 0: Hc quads 0..7
    #pragma unroll
    for (int q = 0; q < 8; ++q) myscr[q ^ sw] = src[q];

    // seed 16 acc quads from the A chain prefix (one-shot gather)
    float4 acc[16];
    #pragma unroll
    for (int j = 0; j < 16; ++j) acc[j] = Ar[j];

    const float* W3b = W3 + 64 * 64;

    // chunk 0: k4 = 0..7 (W3 rows 64..95, ascending)
    #pragma unroll 1
    for (int k4 = 0; k4 < 8; ++k4) {
        const float4 hv = myscr[k4 ^ sw];
        #pragma unroll
        for (int i = 0; i < 4; ++i) {
            const float s = ELEM(hv, i);
            const float* w = W3b + (size_t)(k4 * 4 + i) * 64;
            #pragma unroll
            for (int j = 0; j < 16; ++j) {
                float4 wv = *(const float4*)(w + 4 * j);
                FMA4(acc[j], s, wv);
            }
        }
    }

    // restage chunk 1: Hc quads 8..15 (same L2 lines, fetched once)
    #pragma unroll
    for (int q = 0; q < 8; ++q) myscr[q ^ sw] = src[8 + q];

    // chunk 1: k4 = 8..15 (W3 rows 96..127, ascending)
    #pragma unroll 1
    for (int k4 = 8; k4 < 16; ++k4) {
        const float4 hv = myscr[(k4 - 8) ^ sw];
        #pragma unroll
        for (int i = 0; i < 4; ++i) {
            const float s = ELEM(hv, i);
            const float* w = W3b + (size_t)(k4 * 4 + i) * 64;
            #pragma unroll
            for (int j = 0; j < 16; ++j) {
                float4 wv = *(const float4*)(w + 4 * j);
                FMA4(acc[j], s, wv);
            }
        }
    }

    // + b3, relu (j ascending)
    #pragma unroll
    for (int j = 0; j < 16; ++j) {
        float4 bv = *(const float4*)(b3 + 4 * j);
        acc[j].x = fmaxf(acc[j].x + bv.x, 0.f);
        acc[j].y = fmaxf(acc[j].y + bv.y, 0.f);
        acc[j].z = fmaxf(acc[j].z + bv.z, 0.f);
        acc[j].w = fmaxf(acc[j].w + bv.w, 0.f);
    }

    // logits = (hid @ W4) + b4, j ascending
    float lg[NUM_REL];
    #pragma unroll
    for (int j = 0; j < NUM_REL; ++j) lg[j] = 0.0f;
    #pragma unroll
    for (int jq = 0; jq < 16; ++jq) {
        #pragma unroll
        for (int i = 0; i < 4; ++i) {
            const float s = ELEM(acc[jq], i);
            const float* w = W4 + (size_t)(jq * 4 + i) * NUM_REL;
            #pragma unroll
            for (int j = 0; j < NUM_REL; ++j) lg[j] = fmaf(s, w[j], lg[j]);
        }
    }

    if (!valid) return;

    #pragma unroll
    for (int j = 0; j < NUM_REL; ++j) lg[j] += b4[j];

    // argmax, first occurrence
    int best = 0;
    float bm = lg[0];
    #pragma unroll
    for (int j = 1; j < NUM_REL; ++j)
        if (lg[j] > bm) { bm = lg[j]; best = j; }

    // softmax fp32
    float p[NUM_REL];
    float sum = 0.0f;
    #pragma unroll
    for (int j = 0; j < NUM_REL; ++j) {
        p[j] = expf(lg[j] - bm);
        sum += p[j];
    }
    float inv = 1.0f / sum;

    out_type[e] = (float)best;
    float* op = out_probs + (size_t)e * NUM_REL;
    #pragma unroll
    for (int j = 0; j < NUM_REL; ++j) op[j] = p[j] * inv;
}

// Node pipeline: R17 verbatim (~94 us). Block = 4 waves x 64 lanes; lane =
// node, wave = j-slice via readfirstlane -> SGPR -> s_load weights. h1/h
// handed between layers via LDS [64][65]. Per-element np/BLAS chain: acc=0,
// k ascending fmaf over FULL K, bias AFTER, relu -> bit-identical.
__global__ __launch_bounds__(256, 4) void node_kernel(
    const float* __restrict__ x,
    const float* __restrict__ W1, const float* __restrict__ b1,
    const float* __restrict__ W2, const float* __restrict__ b2,
    const float* __restrict__ W3,
    float* __restrict__ Hout, float* __restrict__ Aout, int N)
{
    __shared__ float h1s[64][65];
    __shared__ float hs[64][65];

    const int tid  = threadIdx.x;
    const int lane = tid & 63;
    const int jb   = __builtin_amdgcn_readfirstlane((tid >> 6) << 4);
    const int n    = blockIdx.x * 64 + lane;
    const bool valid = (n < N);
    const int nc   = valid ? n : (N - 1);

    // ---- L1 slice: h1[jb..jb+16) = relu((x@W1) + b1) ----
    float4 a0 = make_float4(0.f, 0.f, 0.f, 0.f);
    float4 a1 = a0, a2 = a0, a3 = a0;

    const float4* xr = (const float4*)(x + (size_t)nc * NODE_DIM);
    #pragma unroll 1
    for (int k4 = 0; k4 < NODE_DIM / 4; ++k4) {
        float4 xv = xr[k4];
        #pragma unroll
        for (int i = 0; i < 4; ++i) {
            const float s = ELEM(xv, i);
            const float4* w = (const float4*)(W1 + (size_t)(k4 * 4 + i) * 64 + jb);
            float4 w0 = w[0], w1 = w[1], w2 = w[2], w3 = w[3];
            FMA4(a0, s, w0); FMA4(a1, s, w1);
            FMA4(a2, s, w2); FMA4(a3, s, w3);
        }
    }
    {
        const float4* bv = (const float4*)(b1 + jb);
        float4 b0 = bv[0], b1v = bv[1], b2v = bv[2], b3v = bv[3];
        float* d = &h1s[lane][jb];
        d[0]  = fmaxf(a0.x + b0.x, 0.f);  d[1]  = fmaxf(a0.y + b0.y, 0.f);
        d[2]  = fmaxf(a0.z + b0.z, 0.f);  d[3]  = fmaxf(a0.w + b0.w, 0.f);
        d[4]  = fmaxf(a1.x + b1v.x, 0.f); d[5]  = fmaxf(a1.y + b1v.y, 0.f);
        d[6]  = fmaxf(a1.z + b1v.z, 0.f); d[7]  = fmaxf(a1.w + b1v.w, 0.f);
        d[8]  = fmaxf(a2.x + b2v.x, 0.f); d[9]  = fmaxf(a2.y + b2v.y, 0.f);
        d[10] = fmaxf(a2.z + b2v.z, 0.f); d[11] = fmaxf(a2.w + b2v.w, 0.f);
        d[12] = fmaxf(a3.x + b3v.x, 0.f); d[13] = fmaxf(a3.y + b3v.y, 0.f);
        d[14] = fmaxf(a3.z + b3v.z, 0.f); d[15] = fmaxf(a3.w + b3v.w, 0.f);
    }
    __syncthreads();

    // ---- L2 slice: h[jb..jb+16) = (h1@W2) + b2 ----
    a0 = make_float4(0.f, 0.f, 0.f, 0.f); a1 = a0; a2 = a0; a3 = a0;
    #pragma unroll 1
    for (int k = 0; k < 64; ++k) {
        const float s = h1s[lane][k];
        const float4* w = (const float4*)(W2 + (size_t)k * 64 + jb);
        float4 w0 = w[0], w1 = w[1], w2 = w[2], w3 = w[3];
        FMA4(a0, s, w0); FMA4(a1, s, w1);
        FMA4(a2, s, w2); FMA4(a3, s, w3);
    }
    {
        const float4* bv = (const float4*)(b2 + jb);
        float4 b0 = bv[0], b1v = bv[1], b2v = bv[2], b3v = bv[3];
        float4 r0, r1, r2, r3;
        r0.x = a0.x + b0.x;  r0.y = a0.y + b0.y;  r0.z = a0.z + b0.z;  r0.w = a0.w + b0.w;
        r1.x = a1.x + b1v.x; r1.y = a1.y + b1v.y; r1.z = a1.z + b1v.z; r1.w = a1.w + b1v.w;
        r2.x = a2.x + b2v.x; r2.y = a2.y + b2v.y; r2.z = a2.z + b2v.z; r2.w = a2.w + b2v.w;
        r3.x = a3.x + b3v.x; r3.y = a3.y + b3v.y; r3.z = a3.z + b3v.z; r3.w = a3.w + b3v.w;
        float* d = &hs[lane][jb];
        d[0]  = r0.x; d[1]  = r0.y; d[2]  = r0.z; d[3]  = r0.w;
        d[4]  = r1.x; d[5]  = r1.y; d[6]  = r1.z; d[7]  = r1.w;
        d[8]  = r2.x; d[9]  = r2.y; d[10] = r2.z; d[11] = r2.w;
        d[12] = r3.x; d[13] = r3.y; d[14] = r3.z; d[15] = r3.w;
        if (valid) {
            float4* g = (float4*)(Hout + (size_t)n * 64 + jb);
            g[0] = r0; g[1] = r1; g[2] = r2; g[3] = r3;
        }
    }
    __syncthreads();

    // ---- L3 row-half partial slice: A[jb..jb+16) = h @ W3[0:64], no bias ----
    a0 = make_float4(0.f, 0.f, 0.f, 0.f); a1 = a0; a2 = a0; a3 = a0;
    #pragma unroll 1
    for (int k = 0; k < 64; ++k) {
        const float s = hs[lane][k];
        const float4* w = (const float4*)(W3 + (size_t)k * 64 + jb);
        float4 w0 = w[0], w1 = w[1], w2 = w[2], w3 = w[3];
        FMA4(a0, s, w0); FMA4(a1, s, w1);
        FMA4(a2, s, w2); FMA4(a3, s, w3);
    }
    if (valid) {
        float4* g = (float4*)(Aout + (size_t)n * 64 + jb);
        g[0] = a0; g[1] = a1; g[2] = a2; g[3] = a3;
    }
}

extern "C" void kernel_launch(void* const* d_in, const int* in_sizes, int n_in,
                              void* d_out, int out_size, void* d_ws, size_t ws_size,
                              hipStream_t stream)
{
    const float* x  = (const float*)d_in[0];
    const int*   ei = (const int*)d_in[1];
    const float* W1 = (const float*)d_in[2];
    const float* b1 = (const float*)d_in[3];
    const float* W2 = (const float*)d_in[4];
    const float* b2 = (const float*)d_in[5];
    const float* W3 = (const float*)d_in[6];
    const float* b3 = (const float*)d_in[7];
    const float* W4 = (const float*)d_in[8];
    const float* b4 = (const float*)d_in[9];

    int N = in_sizes[0] / NODE_DIM;   // 100000
    int E = in_sizes[1] / 2;          // 1600000

    // ws: H [N*64] f32 | A [N*64] f32   (51.2 MB total)
    float* H = (float*)d_ws;
    float* A = H + (size_t)N * 64;

    int nb = (N + 63) / 64;
    int eb = (E + 255) / 256;

    float* out_type  = (float*)d_out;
    float* out_probs = (float*)d_out + E;

    hipLaunchKernelGGL(node_kernel, dim3(nb), dim3(256), 0, stream,
                       x, W1, b1, W2, b2, W3, H, A, N);
    hipLaunchKernelGGL(edge_kernel, dim3(eb), dim3(256), 0, stream,
                       ei, H, A, W3, b3, W4, b4, out_type, out_probs, E);
}

// Round 25
// 308.230 us; speedup vs baseline: 1.1843x; 1.0130x over previous
//
#include <hip/hip_runtime.h>

#define NODE_DIM 256
#define HIDDEN 64
#define NUM_REL 10

#define FMA4(A, S, W) do { \
    (A).x = fmaf((S), (W).x, (A).x); \
    (A).y = fmaf((S), (W).y, (A).y); \
    (A).z = fmaf((S), (W).z, (A).z); \
    (A).w = fmaf((S), (W).w, (A).w); } while (0)

#define ELEM(V, I) ((I) == 0 ? (V).x : (I) == 1 ? (V).y : (I) == 2 ? (V).z : (V).w)

// Edge kernel: R13/R16-VERBATIM source (the builds where this kernel ran at
// ~71-104 us). R17-R24 showed the same source compiles to a 213 us
// AGPR-shuttle form whenever __builtin_amdgcn_readfirstlane appears anywhere
// in the module (8/8 bad with it, 2/2 good without). This module contains NO
// readfirstlane builtin (node uses inline-asm v_readfirstlane_b32 instead).
// Dataflow: 32 KB per-thread LDS scratch, Hc row staged in two 8-quad
// chunks, each 128B line fetched once. np chain order: k ascending over W3
// rows 64..127, +b3 after, relu, j-ascending logits, +b4 -> bit-identical.
__global__ __launch_bounds__(256, 4) void edge_kernel(
    const int* __restrict__ ei,
    const float* __restrict__ H, const float* __restrict__ A,
    const float* __restrict__ W3, const float* __restrict__ b3,
    const float* __restrict__ W4, const float* __restrict__ b4,
    float* __restrict__ out_type, float* __restrict__ out_probs, int E)
{
    __shared__ float4 HcS[256 * 8];   // 32 KB: per-thread 8-quad scratch

    const int tid = threadIdx.x;
    const int e = blockIdx.x * 256 + tid;
    const bool valid = (e < E);
    const int sw = tid & 7;
    float4* myscr = &HcS[tid * 8];

    const int c = valid ? ei[E + e] : 0;
    const int r = valid ? ei[e] : 0;
    const float4* src = (const float4*)(H + (size_t)c * 64);
    const float4* Ar  = (const float4*)(A + (size_t)r * 64);

    #pragma unroll
    for (int q = 0; q < 8; ++q) myscr[q ^ sw] = src[q];

    float4 acc[16];
    #pragma unroll
    for (int j = 0; j < 16; ++j) acc[j] = Ar[j];

    const float* W3b = W3 + 64 * 64;

    #pragma unroll 1
    for (int k4 = 0; k4 < 8; ++k4) {
        const float4 hv = myscr[k4 ^ sw];
        #pragma unroll
        for (int i = 0; i < 4; ++i) {
            const float s = ELEM(hv, i);
            const float* w = W3b + (size_t)(k4 * 4 + i) * 64;
            #pragma unroll
            for (int j = 0; j < 16; ++j) {
                float4 wv = *(const float4*)(w + 4 * j);
                FMA4(acc[j], s, wv);
            }
        }
    }

    #pragma unroll
    for (int q = 0; q < 8; ++q) myscr[q ^ sw] = src[8 + q];

    #pragma unroll 1
    for (int k4 = 8; k4 < 16; ++k4) {
        const float4 hv = myscr[(k4 - 8) ^ sw];
        #pragma unroll
        for (int i = 0; i < 4; ++i) {
            const float s = ELEM(hv, i);
            const float* w = W3b + (size_t)(k4 * 4 + i) * 64;
            #pragma unroll
            for (int j = 0; j < 16; ++j) {
                float4 wv = *(const float4*)(w + 4 * j);
                FMA4(acc[j], s, wv);
            }
        }
    }

    #pragma unroll
    for (int j = 0; j < 16; ++j) {
        float4 bv = *(const float4*)(b3 + 4 * j);
        acc[j].x = fmaxf(acc[j].x + bv.x, 0.f);
        acc[j].y = fmaxf(acc[j].y + bv.y, 0.f);
        acc[j].z = fmaxf(acc[j].z + bv.z, 0.f);
        acc[j].w = fmaxf(acc[j].w + bv.w, 0.f);
    }

    float lg[NUM_REL];
    #pragma unroll
    for (int j = 0; j < NUM_REL; ++j) lg[j] = 0.0f;
    #pragma unroll
    for (int jq = 0; jq < 16; ++jq) {
        #pragma unroll
        for (int i = 0; i < 4; ++i) {
            const float s = ELEM(acc[jq], i);
            const float* w = W4 + (size_t)(jq * 4 + i) * NUM_REL;
            #pragma unroll
            for (int j = 0; j < NUM_REL; ++j) lg[j] = fmaf(s, w[j], lg[j]);
        }
    }

    if (!valid) return;

    #pragma unroll
    for (int j = 0; j < NUM_REL; ++j) lg[j] += b4[j];

    int best = 0;
    float bm = lg[0];
    #pragma unroll
    for (int j = 1; j < NUM_REL; ++j)
        if (lg[j] > bm) { bm = lg[j]; best = j; }

    float p[NUM_REL];
    float sum = 0.0f;
    #pragma unroll
    for (int j = 0; j < NUM_REL; ++j) {
        p[j] = expf(lg[j] - bm);
        sum += p[j];
    }
    float inv = 1.0f / sum;

    out_type[e] = (float)best;
    float* op = out_probs + (size_t)e * NUM_REL;
    #pragma unroll
    for (int j = 0; j < NUM_REL; ++j) op[j] = p[j] * inv;
}

// Node pipeline: R17 structure (94 us) with ONE change: jb is produced by
// inline-asm v_readfirstlane_b32 (same instruction, same SGPR result) instead
// of __builtin_amdgcn_readfirstlane — removing the builtin from the module to
// test/avoid its module-wide codegen side effect on edge_kernel (rule #19).
// Block = 4 waves x 64 lanes; lane = node, wave = j-slice; h1/h via LDS
// [64][65]. Per-element np/BLAS chain: acc=0, k ascending fmaf over FULL K,
// bias AFTER, relu -> bit-identical.
__global__ __launch_bounds__(256, 4) void node_kernel(
    const float* __restrict__ x,
    const float* __restrict__ W1, const float* __restrict__ b1,
    const float* __restrict__ W2, const float* __restrict__ b2,
    const float* __restrict__ W3,
    float* __restrict__ Hout, float* __restrict__ Aout, int N)
{
    __shared__ float h1s[64][65];
    __shared__ float hs[64][65];

    const int tid  = threadIdx.x;
    const int lane = tid & 63;
    int jb;
    asm("v_readfirstlane_b32 %0, %1" : "=s"(jb) : "v"((tid >> 6) << 4));
    const int n    = blockIdx.x * 64 + lane;
    const bool valid = (n < N);
    const int nc   = valid ? n : (N - 1);

    // ---- L1 slice: h1[jb..jb+16) = relu((x@W1) + b1) ----
    float4 a0 = make_float4(0.f, 0.f, 0.f, 0.f);
    float4 a1 = a0, a2 = a0, a3 = a0;

    const float4* xr = (const float4*)(x + (size_t)nc * NODE_DIM);
    #pragma unroll 1
    for (int k4 = 0; k4 < NODE_DIM / 4; ++k4) {
        float4 xv = xr[k4];
        #pragma unroll
        for (int i = 0; i < 4; ++i) {
            const float s = ELEM(xv, i);
            const float4* w = (const float4*)(W1 + (size_t)(k4 * 4 + i) * 64 + jb);
            float4 w0 = w[0], w1 = w[1], w2 = w[2], w3 = w[3];
            FMA4(a0, s, w0); FMA4(a1, s, w1);
            FMA4(a2, s, w2); FMA4(a3, s, w3);
        }
    }
    {
        const float4* bv = (const float4*)(b1 + jb);
        float4 b0 = bv[0], b1v = bv[1], b2v = bv[2], b3v = bv[3];
        float* d = &h1s[lane][jb];
        d[0]  = fmaxf(a0.x + b0.x, 0.f);  d[1]  = fmaxf(a0.y + b0.y, 0.f);
        d[2]  = fmaxf(a0.z + b0.z, 0.f);  d[3]  = fmaxf(a0.w + b0.w, 0.f);
        d[4]  = fmaxf(a1.x + b1v.x, 0.f); d[5]  = fmaxf(a1.y + b1v.y, 0.f);
        d[6]  = fmaxf(a1.z + b1v.z, 0.f); d[7]  = fmaxf(a1.w + b1v.w, 0.f);
        d[8]  = fmaxf(a2.x + b2v.x, 0.f); d[9]  = fmaxf(a2.y + b2v.y, 0.f);
        d[10] = fmaxf(a2.z + b2v.z, 0.f); d[11] = fmaxf(a2.w + b2v.w, 0.f);
        d[12] = fmaxf(a3.x + b3v.x, 0.f); d[13] = fmaxf(a3.y + b3v.y, 0.f);
        d[14] = fmaxf(a3.z + b3v.z, 0.f); d[15] = fmaxf(a3.w + b3v.w, 0.f);
    }
    __syncthreads();

    // ---- L2 slice: h[jb..jb+16) = (h1@W2) + b2 ----
    a0 = make_float4(0.f, 0.f, 0.f, 0.f); a1 = a0; a2 = a0; a3 = a0;
    #pragma unroll 1
    for (int k = 0; k < 64; ++k) {
        const float s = h1s[lane][k];
        const float4* w = (const float4*)(W2 + (size_t)k * 64 + jb);
        float4 w0 = w[0], w1 = w[1], w2 = w[2], w3 = w[3];
        FMA4(a0, s, w0); FMA4(a1, s, w1);
        FMA4(a2, s, w2); FMA4(a3, s, w3);
    }
    {
        const float4* bv = (const float4*)(b2 + jb);
        float4 b0 = bv[0], b1v = bv[1], b2v = bv[2], b3v = bv[3];
        float4 r0, r1, r2, r3;
        r0.x = a0.x + b0.x;  r0.y = a0.y + b0.y;  r0.z = a0.z + b0.z;  r0.w = a0.w + b0.w;
        r1.x = a1.x + b1v.x; r1.y = a1.y + b1v.y; r1.z = a1.z + b1v.z; r1.w = a1.w + b1v.w;
        r2.x = a2.x + b2v.x; r2.y = a2.y + b2v.y; r2.z = a2.z + b2v.z; r2.w = a2.w + b2v.w;
        r3.x = a3.x + b3v.x; r3.y = a3.y + b3v.y; r3.z = a3.z + b3v.z; r3.w = a3.w + b3v.w;
        float* d = &hs[lane][jb];
        d[0]  = r0.x; d[1]  = r0.y; d[2]  = r0.z; d[3]  = r0.w;
        d[4]  = r1.x; d[5]  = r1.y; d[6]  = r1.z; d[7]  = r1.w;
        d[8]  = r2.x; d[9]  = r2.y; d[10] = r2.z; d[11] = r2.w;
        d[12] = r3.x; d[13] = r3.y; d[14] = r3.z; d[15] = r3.w;
        if (valid) {
            float4* g = (float4*)(Hout + (size_t)n * 64 + jb);
            g[0] = r0; g[1] = r1; g[2] = r2; g[3] = r3;
        }
    }
    __syncthreads();

    // ---- L3 row-half partial slice: A[jb..jb+16) = h @ W3[0:64], no bias ----
    a0 = make_float4(0.f, 0.f, 0.f, 0.f); a1 = a0; a2 = a0; a3 = a0;
    #pragma unroll 1
    for (int k = 0; k < 64; ++k) {
        const float s = hs[lane][k];
        const float4* w = (const float4*)(W3 + (size_t)k * 64 + jb);
        float4 w0 = w[0], w1 = w[1], w2 = w[2], w3 = w[3];
        FMA4(a0, s, w0); FMA4(a1, s, w1);
        FMA4(a2, s, w2); FMA4(a3, s, w3);
    }
    if (valid) {
        float4* g = (float4*)(Aout + (size_t)n * 64 + jb);
        g[0] = a0; g[1] = a1; g[2] = a2; g[3] = a3;
    }
}

extern "C" void kernel_launch(void* const* d_in, const int* in_sizes, int n_in,
                              void* d_out, int out_size, void* d_ws, size_t ws_size,
                              hipStream_t stream)
{
    const float* x  = (const float*)d_in[0];
    const int*   ei = (const int*)d_in[1];
    const float* W1 = (const float*)d_in[2];
    const float* b1 = (const float*)d_in[3];
    const float* W2 = (const float*)d_in[4];
    const float* b2 = (const float*)d_in[5];
    const float* W3 = (const float*)d_in[6];
    const float* b3 = (const float*)d_in[7];
    const float* W4 = (const float*)d_in[8];
    const float* b4 = (const float*)d_in[9];

    int N = in_sizes[0] / NODE_DIM;   // 100000
    int E = in_sizes[1] / 2;          // 1600000

    // ws: H [N*64] f32 | A [N*64] f32   (51.2 MB total)
    float* H = (float*)d_ws;
    float* A = H + (size_t)N * 64;

    int nb = (N + 63) / 64;
    int eb = (E + 255) / 256;

    float* out_type  = (float*)d_out;
    float* out_probs = (float*)d_out + E;

    hipLaunchKernelGGL(node_kernel, dim3(nb), dim3(256), 0, stream,
                       x, W1, b1, W2, b2, W3, H, A, N);
    hipLaunchKernelGGL(edge_kernel, dim3(eb), dim3(256), 0, stream,
                       ei, H, A, W3, b3, W4, b4, out_type, out_probs, E);
}